// Round 10
// baseline (391.723 us; speedup 1.0000x reference)
//
#include <hip/hip_runtime.h>
#include <hip/hip_bf16.h>

typedef __attribute__((ext_vector_type(8))) short short8;
typedef __attribute__((ext_vector_type(4))) float f32x4;

#define S_DIM 384
#define N_DIM 512
#define C_DIM 32
#define CZ_DIM 128
#define MROWS (S_DIM * C_DIM)   /* 12288 */
#define NCELL (S_DIM * S_DIM)   /* 147456 */

__device__ __forceinline__ void async16(const void* g, void* l) {
  __builtin_amdgcn_global_load_lds(
      (const __attribute__((address_space(1))) void*)g,
      (__attribute__((address_space(3))) void*)l, 16, 0, 0);
}

// Kernel 1: LayerNorm + w_ab projection.
__global__ __launch_bounds__(256) void prep_kernel(
    const float* __restrict__ m_si, const float* __restrict__ ln_g,
    const float* __restrict__ ln_b, const float* __restrict__ w_ab,
    __hip_bfloat16* __restrict__ Abt, __hip_bfloat16* __restrict__ Bbt) {
  const int n = blockIdx.x * 256 + threadIdx.x;  // 0..511
  const int s = blockIdx.y;                      // 0..383
  const float* x = m_si + ((size_t)s * N_DIM + n) * C_DIM;

  float v[C_DIM];
#pragma unroll
  for (int i = 0; i < 8; ++i) {
    float4 t = ((const float4*)x)[i];
    v[4 * i + 0] = t.x; v[4 * i + 1] = t.y;
    v[4 * i + 2] = t.z; v[4 * i + 3] = t.w;
  }
  float sum = 0.f;
#pragma unroll
  for (int c = 0; c < C_DIM; ++c) sum += v[c];
  const float mu = sum * (1.f / 32.f);
  float sq = 0.f;
#pragma unroll
  for (int c = 0; c < C_DIM; ++c) { float d = v[c] - mu; sq += d * d; }
  const float rstd = rsqrtf(sq * (1.f / 32.f) + 1e-5f);

  float mn[C_DIM];
#pragma unroll
  for (int c = 0; c < C_DIM; ++c)
    mn[c] = (v[c] - mu) * rstd * ln_g[c] + ln_b[c];

#pragma unroll 4
  for (int d = 0; d < 32; ++d) {
    float aA = 0.f, aB = 0.f;
#pragma unroll
    for (int c = 0; c < C_DIM; ++c) {
      aA += mn[c] * w_ab[d * C_DIM + c];
      aB += mn[c] * w_ab[(d + 32) * C_DIM + c];
    }
    Abt[((size_t)(s * 32 + d)) * N_DIM + n] = __float2bfloat16(aA * (1.f / 512.f));
    Bbt[((size_t)(s * 32 + d)) * N_DIM + n] = __float2bfloat16(aB);
  }
}

// Kernel 2: w_final fp32 -> bf16 (128 x 1024)
__global__ __launch_bounds__(256) void conv_wf(const float* __restrict__ w_final,
                                               __hip_bfloat16* __restrict__ Wf) {
  const int i = blockIdx.x * 256 + threadIdx.x;
  Wf[i] = __float2bfloat16(w_final[i]);
}

// Kernel 3 (split path): COMBINED role-split kernel.
//   blockIdx.x <  zN : zgemm role  — Z tile from O slab s-1 (OgR) -> outp.
//   blockIdx.x >= zN : opm role    — outer-product GEMM slab s -> OgW.
// Same-stream launches serialize, so opm(s-1) completed before launch s;
// within launch s the roles touch disjoint O buffers -> zgemm(s-1) overlaps
// opm(s). zgemm blocks first so the memory-bound role co-schedules with the
// LDS/MFMA-bound role from dispatch start. Both bodies verbatim from R9.
__global__ __launch_bounds__(256, 2) void combined(
    const __hip_bfloat16* __restrict__ Abt, const __hip_bfloat16* __restrict__ Bbt,
    const __hip_bfloat16* __restrict__ Wf, const float* __restrict__ b_final,
    __hip_bfloat16* __restrict__ OgW, const __hip_bfloat16* __restrict__ OgR,
    float* __restrict__ outp, int bi0, int zN) {
  __shared__ __align__(16) char smem[32768];

  const int tid = threadIdx.x;
  const int wave = tid >> 6;
  const int lane = tid & 63;
  const int fr = lane & 15;
  const int fq = lane >> 4;
  const int fqs = fq ^ ((fr >> 1) & 3);  // swizzled physical k-slot
  const int wr = wave >> 1, wc = wave & 1;
  const int srow = tid >> 2;
  const int sk = (((tid & 3) ^ ((tid >> 3) & 3)) * 8);  // pre-swizzled k offset
  const int ldst = tid * 16;
  const f32x4 fzero = {0.f, 0.f, 0.f, 0.f};

  if (blockIdx.x < (unsigned)zN) {
    // ---------------- zgemm role: Z[128 cells][128 z] ----------------
    const size_t cell0 = (size_t)blockIdx.x * 128;
    const __hip_bfloat16* gO = OgR + (cell0 + srow) * 1024 + sk;
    const __hip_bfloat16* gW = Wf + (size_t)srow * 1024 + sk;

    f32x4 acc[4][4];
#pragma unroll
    for (int i = 0; i < 4; ++i)
#pragma unroll
      for (int j = 0; j < 4; ++j) acc[i][j] = fzero;

    auto stage = [&](int kt, char* base) {
      const int k0 = kt * 32;
      async16(gO + k0, base + ldst);
      async16(gO + (size_t)64 * 1024 + k0, base + 4096 + ldst);
      async16(gW + k0, base + 8192 + ldst);
      async16(gW + (size_t)64 * 1024 + k0, base + 12288 + ldst);
    };
    auto compute = [&](const char* base) {
      const __hip_bfloat16* As = (const __hip_bfloat16*)base;
      const __hip_bfloat16* Bs = (const __hip_bfloat16*)(base + 8192);
      short8 af[4], bfr[4];
#pragma unroll
      for (int mt = 0; mt < 4; ++mt)
        af[mt] = *(const short8*)(As + (wr * 64 + mt * 16 + fr) * 32 + fqs * 8);
#pragma unroll
      for (int nt = 0; nt < 4; ++nt)
        bfr[nt] = *(const short8*)(Bs + (wc * 64 + nt * 16 + fr) * 32 + fqs * 8);
#pragma unroll
      for (int mt = 0; mt < 4; ++mt)
#pragma unroll
        for (int nt = 0; nt < 4; ++nt)
          acc[mt][nt] = __builtin_amdgcn_mfma_f32_16x16x32_bf16(
              af[mt], bfr[nt], acc[mt][nt], 0, 0, 0);
    };

    char* buf0 = smem;
    char* buf1 = smem + 16384;
    stage(0, buf0);
    __syncthreads();
    for (int kt = 0; kt < 32; kt += 2) {
      stage(kt + 1, buf1);
      compute(buf0);
      __syncthreads();
      if (kt + 2 < 32) stage(kt + 2, buf0);
      compute(buf1);
      __syncthreads();
    }

#pragma unroll
    for (int nt = 0; nt < 4; ++nt) {
      const int zcol = wc * 64 + nt * 16 + fr;
      const float bz = b_final[zcol];
#pragma unroll
      for (int mt = 0; mt < 4; ++mt) {
        const size_t zrow = cell0 + wr * 64 + mt * 16 + fq * 4;
#pragma unroll
        for (int r = 0; r < 4; ++r)
          outp[(zrow + r) * CZ_DIM + zcol] = acc[mt][nt][r] + bz;
      }
    }
  } else {
    // ---------------- opm role: O tile for slab bi0 ----------------
    // XCD bj-band remap (opm block count always % 8 == 0).
    const int f = blockIdx.x - zN;
    const int xcd = f & 7;
    const int i_ = f >> 3;
    const int bj = xcd * 12 + (i_ % 12);   // 12-column band per XCD
    const int biL = i_ / 12;               // slab-local block row

    const size_t m0 = (size_t)(bi0 + biL) * 128;
    const size_t n0 = (size_t)bj * 128;
    const __hip_bfloat16* gA = Abt + (m0 + srow) * N_DIM + sk;
    const __hip_bfloat16* gB = Bbt + (n0 + srow) * N_DIM + sk;

    f32x4 acc[4][4];
#pragma unroll
    for (int i = 0; i < 4; ++i)
#pragma unroll
      for (int j = 0; j < 4; ++j) acc[i][j] = fzero;

    auto stage = [&](int kt, char* base) {
      const int k0 = kt * 32;
      async16(gA + k0, base + ldst);
      async16(gA + (size_t)64 * N_DIM + k0, base + 4096 + ldst);
      async16(gB + k0, base + 8192 + ldst);
      async16(gB + (size_t)64 * N_DIM + k0, base + 12288 + ldst);
    };
    auto compute = [&](const char* base) {
      const __hip_bfloat16* As = (const __hip_bfloat16*)base;
      const __hip_bfloat16* Bs = (const __hip_bfloat16*)(base + 8192);
      short8 af[4], bfr[4];
#pragma unroll
      for (int mt = 0; mt < 4; ++mt)
        af[mt] = *(const short8*)(As + (wr * 64 + mt * 16 + fr) * 32 + fqs * 8);
#pragma unroll
      for (int nt = 0; nt < 4; ++nt)
        bfr[nt] = *(const short8*)(Bs + (wc * 64 + nt * 16 + fr) * 32 + fqs * 8);
#pragma unroll
      for (int mt = 0; mt < 4; ++mt)
#pragma unroll
        for (int nt = 0; nt < 4; ++nt)
          acc[mt][nt] = __builtin_amdgcn_mfma_f32_16x16x32_bf16(
              af[mt], bfr[nt], acc[mt][nt], 0, 0, 0);
    };

    char* buf0 = smem;
    char* buf1 = smem + 16384;
    stage(0, buf0);
    __syncthreads();
    for (int kt = 0; kt < 16; kt += 2) {
      stage(kt + 1, buf1);
      compute(buf0);
      __syncthreads();
      if (kt + 2 < 16) stage(kt + 2, buf0);
      compute(buf1);
      __syncthreads();
    }

    // Phase 1: acc -> Oc LDS bf16, slot-swizzled (32 KB = 16 cells x 1024).
    __hip_bfloat16* Oc = (__hip_bfloat16*)smem;
#pragma unroll
    for (int mt = 0; mt < 4; ++mt) {
#pragma unroll
      for (int nt = 0; nt < 4; ++nt) {
        const int orow_b = wr * 64 + mt * 16 + fq * 4;
        const int ocol = wc * 64 + nt * 16 + fr;  // C/D map: col=lane&15
#pragma unroll
        for (int r = 0; r < 4; ++r) {             // row=(lane>>4)*4+reg
          const int orow = orow_b + r;
          const int cell = ((orow >> 5) << 2) + (ocol >> 5);  // li*4+lj
          const int kk = ((orow & 31) << 5) + (ocol & 31);    // c*32+d
          const int sw = ((((kk >> 3) ^ (cell & 7)) << 3) | (kk & 7));
          Oc[cell * 1024 + sw] = __float2bfloat16(acc[mt][nt][r]);
        }
      }
    }
    __syncthreads();

    // Phase 2: de-swizzled, coalesced b128 O-store. 8 x 16B per thread.
    const __hip_bfloat16* OcR = (const __hip_bfloat16*)smem;
#pragma unroll
    for (int j = 0; j < 8; ++j) {
      const int lc = j * 256 + tid;   // logical 16B-chunk index, 0..2047
      const int cellL = lc >> 7;      // 0..15
      const int ch = lc & 127;        // chunk within cell (kk>>3)
      const int phys = (ch & ~7) | ((ch & 7) ^ (cellL & 7));
      const short8 val = *(const short8*)(OcR + cellL * 1024 + phys * 8);
      const int li = cellL >> 2, lj = cellL & 3;
      __hip_bfloat16* dst =
          OgW + ((size_t)((biL * 4 + li) * S_DIM + (bj * 4 + lj))) * 1024 + ch * 8;
      *(short8*)dst = val;
    }
  }
}

// Legacy fused kernel (R3) — fallback when workspace can't hold any O slab.
__global__ __launch_bounds__(256, 2) void fused_opm(
    const __hip_bfloat16* __restrict__ Abt, const __hip_bfloat16* __restrict__ Bbt,
    const __hip_bfloat16* __restrict__ Wf, const float* __restrict__ b_final,
    float* __restrict__ out) {
  __shared__ __align__(16) char smem[32768];
  const int tid = threadIdx.x;
  const int wave = tid >> 6;
  const int lane = tid & 63;
  const int fr = lane & 15;
  const int fq = lane >> 4;
  const int fqs = fq ^ ((fr >> 1) & 3);
  const int wr = wave >> 1, wc = wave & 1;
  const int bi = blockIdx.y, bj = blockIdx.x;
  const size_t m0 = (size_t)bi * 128;
  const size_t n0 = (size_t)bj * 128;
  const int srow = tid >> 2;
  const int sk = (((tid & 3) ^ ((tid >> 3) & 3)) * 8);
  const __hip_bfloat16* gA = Abt + (m0 + srow) * N_DIM + sk;
  const __hip_bfloat16* gB = Bbt + (n0 + srow) * N_DIM + sk;
  const int ldst = tid * 16;

  const f32x4 fzero = {0.f, 0.f, 0.f, 0.f};
  f32x4 acc[4][4];
#pragma unroll
  for (int i = 0; i < 4; ++i)
#pragma unroll
    for (int j = 0; j < 4; ++j) acc[i][j] = fzero;

  auto stage = [&](int kt, char* base) {
    const int k0 = kt * 32;
    async16(gA + k0, base + ldst);
    async16(gA + (size_t)64 * N_DIM + k0, base + 4096 + ldst);
    async16(gB + k0, base + 8192 + ldst);
    async16(gB + (size_t)64 * N_DIM + k0, base + 12288 + ldst);
  };
  auto compute = [&](const char* base) {
    const __hip_bfloat16* As = (const __hip_bfloat16*)base;
    const __hip_bfloat16* Bs = (const __hip_bfloat16*)(base + 8192);
    short8 af[4], bfr[4];
#pragma unroll
    for (int mt = 0; mt < 4; ++mt)
      af[mt] = *(const short8*)(As + (wr * 64 + mt * 16 + fr) * 32 + fqs * 8);
#pragma unroll
    for (int nt = 0; nt < 4; ++nt)
      bfr[nt] = *(const short8*)(Bs + (wc * 64 + nt * 16 + fr) * 32 + fqs * 8);
#pragma unroll
    for (int mt = 0; mt < 4; ++mt)
#pragma unroll
      for (int nt = 0; nt < 4; ++nt)
        acc[mt][nt] = __builtin_amdgcn_mfma_f32_16x16x32_bf16(
            af[mt], bfr[nt], acc[mt][nt], 0, 0, 0);
  };

  char* buf0 = smem;
  char* buf1 = smem + 16384;
  stage(0, buf0);
  __syncthreads();
  for (int kt = 0; kt < 16; kt += 2) {
    stage(kt + 1, buf1);
    compute(buf0);
    __syncthreads();
    if (kt + 2 < 16) stage(kt + 2, buf0);
    compute(buf1);
    __syncthreads();
  }

  __hip_bfloat16* Oc = (__hip_bfloat16*)smem;  // [16][1024] slot-swizzled
#pragma unroll
  for (int mt = 0; mt < 4; ++mt) {
#pragma unroll
    for (int nt = 0; nt < 4; ++nt) {
      const int orow_b = wr * 64 + mt * 16 + fq * 4;
      const int ocol = wc * 64 + nt * 16 + fr;
#pragma unroll
      for (int r = 0; r < 4; ++r) {
        const int orow = orow_b + r;
        const int cell = ((orow >> 5) << 2) + (ocol >> 5);
        const int kk = ((orow & 31) << 5) + (ocol & 31);
        const int sw = ((((kk >> 3) ^ (cell & 7)) << 3) | (kk & 7));
        Oc[cell * 1024 + sw] = __float2bfloat16(acc[mt][nt][r]);
      }
    }
  }
  __syncthreads();

  f32x4 zacc0 = fzero, zacc1 = fzero;
  const int zt0 = wave * 2;
  const int xr = fr & 7;
  for (int kk = 0; kk < 32; ++kk) {
    const int slot = kk * 4 + fq;
    const short8 oa = *(const short8*)(Oc + fr * 1024 + ((slot ^ xr) << 3));
    const short8 wb0 =
        *(const short8*)(Wf + (size_t)((zt0 + 0) * 16 + fr) * 1024 + kk * 32 + fq * 8);
    const short8 wb1 =
        *(const short8*)(Wf + (size_t)((zt0 + 1) * 16 + fr) * 1024 + kk * 32 + fq * 8);
    zacc0 = __builtin_amdgcn_mfma_f32_16x16x32_bf16(oa, wb0, zacc0, 0, 0, 0);
    zacc1 = __builtin_amdgcn_mfma_f32_16x16x32_bf16(oa, wb1, zacc1, 0, 0, 0);
  }

  const int i0 = bi * 4, j0 = bj * 4;
#pragma unroll
  for (int t = 0; t < 2; ++t) {
    const int zcol = (zt0 + t) * 16 + fr;
    const float bz = b_final[zcol];
    const f32x4 za = t ? zacc1 : zacc0;
#pragma unroll
    for (int r = 0; r < 4; ++r) {
      const int cell = fq * 4 + r;
      const int li = cell >> 2, lj = cell & 3;
      out[((size_t)(i0 + li) * S_DIM + (j0 + lj)) * CZ_DIM + zcol] = za[r] + bz;
    }
  }
}

extern "C" void kernel_launch(void* const* d_in, const int* in_sizes, int n_in,
                              void* d_out, int out_size, void* d_ws, size_t ws_size,
                              hipStream_t stream) {
  const float* m_si = (const float*)d_in[0];
  const float* ln_g = (const float*)d_in[1];
  const float* ln_b = (const float*)d_in[2];
  const float* w_ab = (const float*)d_in[3];
  const float* w_final = (const float*)d_in[4];
  const float* b_final = (const float*)d_in[5];
  float* out = (float*)d_out;

  char* ws = (char*)d_ws;
  __hip_bfloat16* Abt = (__hip_bfloat16*)ws;                                // 12.58 MB
  __hip_bfloat16* Bbt = (__hip_bfloat16*)(ws + (size_t)MROWS * N_DIM * 2);  // 12.58 MB
  __hip_bfloat16* Wf = (__hip_bfloat16*)(ws + (size_t)MROWS * N_DIM * 4);   // 256 KB
  const size_t base = (size_t)MROWS * N_DIM * 4 + 262144;

  prep_kernel<<<dim3(2, S_DIM), 256, 0, stream>>>(m_si, ln_g, ln_b, w_ab, Abt, Bbt);
  conv_wf<<<dim3((CZ_DIM * 1024) / 256), 256, 0, stream>>>(w_final, Wf);

  // --- Pipelined path: npair slabs, 2 O buffers, opm(s) || zgemm(s-1). ---
  static const int pairs[] = {4, 8, 16};
  int npair = 0;
  for (int c : pairs) {
    if (base + 2 * ((size_t)NCELL / c) * 1024 * 2 <= ws_size) { npair = c; break; }
  }

  if (npair) {
    const int biPer = 96 / npair;
    const size_t cellsPer = (size_t)NCELL / npair;
    const size_t slabBytes = cellsPer * 1024 * 2;
    const int zB = (int)(cellsPer / 128);   // zgemm blocks per slab
    const int oB = 96 * biPer;              // opm blocks per slab (%8==0)
    __hip_bfloat16* Ob[2] = {(__hip_bfloat16*)(ws + base),
                             (__hip_bfloat16*)(ws + base + slabBytes)};
    for (int s = 0; s <= npair; ++s) {
      const int zN = (s > 0) ? zB : 0;
      const int grid = zN + ((s < npair) ? oB : 0);
      combined<<<grid, 256, 0, stream>>>(
          Abt, Bbt, Wf, b_final,
          Ob[s & 1], Ob[(s + 1) & 1],
          out + (size_t)(s - 1) * cellsPer * CZ_DIM,  // unused when s==0
          s * biPer, zN);
    }
    return;
  }

  // --- Sequential split fallback: one O buffer, serial opm -> zgemm. ---
  static const int cands[] = {2, 3, 4, 6, 8, 12, 16, 24, 32};
  int nslab = 0;
  for (int c : cands) {
    if (base + ((size_t)NCELL / c) * 1024 * 2 <= ws_size) { nslab = c; break; }
  }

  if (nslab) {
    const int biPer = 96 / nslab;
    const size_t cellsPer = (size_t)NCELL / nslab;
    const int zB = (int)(cellsPer / 128);
    const int oB = 96 * biPer;
    __hip_bfloat16* Og = (__hip_bfloat16*)(ws + base);
    for (int s = 0; s < nslab; ++s) {
      combined<<<oB, 256, 0, stream>>>(Abt, Bbt, Wf, b_final, Og, Og,
                                       out, s * biPer, 0);
      combined<<<zB, 256, 0, stream>>>(Abt, Bbt, Wf, b_final, Og, Og,
                                       out + (size_t)s * cellsPer * CZ_DIM,
                                       0, zB);
    }
  } else {
    fused_opm<<<dim3(96, 96), 256, 0, stream>>>(Abt, Bbt, Wf, b_final, out);
  }
}

// Round 11
// 379.484 us; speedup vs baseline: 1.0323x; 1.0323x over previous
//
#include <hip/hip_runtime.h>
#include <hip/hip_bf16.h>

typedef __attribute__((ext_vector_type(8))) short short8;
typedef __attribute__((ext_vector_type(4))) float f32x4;

#define S_DIM 384
#define N_DIM 512
#define C_DIM 32
#define CZ_DIM 128
#define MROWS (S_DIM * C_DIM)   /* 12288 */
#define NCELL (S_DIM * S_DIM)   /* 147456 */

__device__ __forceinline__ void async16(const void* g, void* l) {
  __builtin_amdgcn_global_load_lds(
      (const __attribute__((address_space(1))) void*)g,
      (__attribute__((address_space(3))) void*)l, 16, 0, 0);
}

// Kernel 1: LayerNorm + w_ab projection.
__global__ __launch_bounds__(256) void prep_kernel(
    const float* __restrict__ m_si, const float* __restrict__ ln_g,
    const float* __restrict__ ln_b, const float* __restrict__ w_ab,
    __hip_bfloat16* __restrict__ Abt, __hip_bfloat16* __restrict__ Bbt) {
  const int n = blockIdx.x * 256 + threadIdx.x;  // 0..511
  const int s = blockIdx.y;                      // 0..383
  const float* x = m_si + ((size_t)s * N_DIM + n) * C_DIM;

  float v[C_DIM];
#pragma unroll
  for (int i = 0; i < 8; ++i) {
    float4 t = ((const float4*)x)[i];
    v[4 * i + 0] = t.x; v[4 * i + 1] = t.y;
    v[4 * i + 2] = t.z; v[4 * i + 3] = t.w;
  }
  float sum = 0.f;
#pragma unroll
  for (int c = 0; c < C_DIM; ++c) sum += v[c];
  const float mu = sum * (1.f / 32.f);
  float sq = 0.f;
#pragma unroll
  for (int c = 0; c < C_DIM; ++c) { float d = v[c] - mu; sq += d * d; }
  const float rstd = rsqrtf(sq * (1.f / 32.f) + 1e-5f);

  float mn[C_DIM];
#pragma unroll
  for (int c = 0; c < C_DIM; ++c)
    mn[c] = (v[c] - mu) * rstd * ln_g[c] + ln_b[c];

#pragma unroll 4
  for (int d = 0; d < 32; ++d) {
    float aA = 0.f, aB = 0.f;
#pragma unroll
    for (int c = 0; c < C_DIM; ++c) {
      aA += mn[c] * w_ab[d * C_DIM + c];
      aB += mn[c] * w_ab[(d + 32) * C_DIM + c];
    }
    Abt[((size_t)(s * 32 + d)) * N_DIM + n] = __float2bfloat16(aA * (1.f / 512.f));
    Bbt[((size_t)(s * 32 + d)) * N_DIM + n] = __float2bfloat16(aB);
  }
}

// Kernel 2: w_final fp32 -> bf16 (128 x 1024)
__global__ __launch_bounds__(256) void conv_wf(const float* __restrict__ w_final,
                                               __hip_bfloat16* __restrict__ Wf) {
  const int i = blockIdx.x * 256 + threadIdx.x;
  Wf[i] = __float2bfloat16(w_final[i]);
}

// Kernel 3a: main outer-product GEMM (one i-slab). 128x128 tile, K=512,
// 4 waves 2x2, dbuf + k-slot swizzle + XCD bj-band remap (R8, proven).
__global__ __launch_bounds__(256, 2) void opm_main(
    const __hip_bfloat16* __restrict__ Abt, const __hip_bfloat16* __restrict__ Bbt,
    __hip_bfloat16* __restrict__ Og, int bi0) {
  __shared__ __align__(16) char smem[32768];

  const int tid = threadIdx.x;
  const int wave = tid >> 6;
  const int lane = tid & 63;
  const int fr = lane & 15;
  const int fq = lane >> 4;
  const int fqs = fq ^ ((fr >> 1) & 3);  // swizzled physical k-slot
  const int wr = wave >> 1, wc = wave & 1;

  // XCD bj-band remap.
  const int f = blockIdx.y * 96 + blockIdx.x;
  const int xcd = f & 7;
  const int i_ = f >> 3;
  const int bj = xcd * 12 + (i_ % 12);   // 12-column band per XCD
  const int biL = i_ / 12;               // slab-local block row

  const size_t m0 = (size_t)(bi0 + biL) * 128;
  const size_t n0 = (size_t)bj * 128;

  const int srow = tid >> 2;
  const int sk = (((tid & 3) ^ ((tid >> 3) & 3)) * 8);  // pre-swizzled k offset
  const __hip_bfloat16* gA = Abt + (m0 + srow) * N_DIM + sk;
  const __hip_bfloat16* gB = Bbt + (n0 + srow) * N_DIM + sk;
  const int ldst = tid * 16;

  const f32x4 fzero = {0.f, 0.f, 0.f, 0.f};
  f32x4 acc[4][4];
#pragma unroll
  for (int i = 0; i < 4; ++i)
#pragma unroll
    for (int j = 0; j < 4; ++j) acc[i][j] = fzero;

  auto stage = [&](int kt, char* base) {
    const int k0 = kt * 32;
    async16(gA + k0, base + ldst);
    async16(gA + (size_t)64 * N_DIM + k0, base + 4096 + ldst);
    async16(gB + k0, base + 8192 + ldst);
    async16(gB + (size_t)64 * N_DIM + k0, base + 12288 + ldst);
  };
  auto compute = [&](const char* base) {
    const __hip_bfloat16* As = (const __hip_bfloat16*)base;
    const __hip_bfloat16* Bs = (const __hip_bfloat16*)(base + 8192);
    short8 af[4], bfr[4];
#pragma unroll
    for (int mt = 0; mt < 4; ++mt)
      af[mt] = *(const short8*)(As + (wr * 64 + mt * 16 + fr) * 32 + fqs * 8);
#pragma unroll
    for (int nt = 0; nt < 4; ++nt)
      bfr[nt] = *(const short8*)(Bs + (wc * 64 + nt * 16 + fr) * 32 + fqs * 8);
#pragma unroll
    for (int mt = 0; mt < 4; ++mt)
#pragma unroll
      for (int nt = 0; nt < 4; ++nt)
        acc[mt][nt] = __builtin_amdgcn_mfma_f32_16x16x32_bf16(
            af[mt], bfr[nt], acc[mt][nt], 0, 0, 0);
  };

  char* buf0 = smem;
  char* buf1 = smem + 16384;
  stage(0, buf0);
  __syncthreads();
  for (int kt = 0; kt < 16; kt += 2) {
    stage(kt + 1, buf1);
    compute(buf0);
    __syncthreads();
    if (kt + 2 < 16) stage(kt + 2, buf0);
    compute(buf1);
    __syncthreads();
  }

  // Phase 1: acc -> Oc LDS bf16, slot-swizzled (32 KB = 16 cells x 1024).
  __hip_bfloat16* Oc = (__hip_bfloat16*)smem;
#pragma unroll
  for (int mt = 0; mt < 4; ++mt) {
#pragma unroll
    for (int nt = 0; nt < 4; ++nt) {
      const int orow_b = wr * 64 + mt * 16 + fq * 4;
      const int ocol = wc * 64 + nt * 16 + fr;  // C/D map: col=lane&15
#pragma unroll
      for (int r = 0; r < 4; ++r) {             // row=(lane>>4)*4+reg
        const int orow = orow_b + r;
        const int cell = ((orow >> 5) << 2) + (ocol >> 5);  // li*4+lj
        const int kk = ((orow & 31) << 5) + (ocol & 31);    // c*32+d
        const int sw = ((((kk >> 3) ^ (cell & 7)) << 3) | (kk & 7));
        Oc[cell * 1024 + sw] = __float2bfloat16(acc[mt][nt][r]);
      }
    }
  }
  __syncthreads();

  // Phase 2: de-swizzled, coalesced b128 O-store. 8 x 16B per thread.
  const __hip_bfloat16* OcR = (const __hip_bfloat16*)smem;
#pragma unroll
  for (int j = 0; j < 8; ++j) {
    const int lc = j * 256 + tid;   // logical 16B-chunk index, 0..2047
    const int cellL = lc >> 7;      // 0..15
    const int ch = lc & 127;        // chunk within cell (kk>>3)
    const int phys = (ch & ~7) | ((ch & 7) ^ (cellL & 7));
    const short8 val = *(const short8*)(OcR + cellL * 1024 + phys * 8);
    const int li = cellL >> 2, lj = cellL & 3;
    __hip_bfloat16* dst =
        Og + ((size_t)((biL * 4 + li) * S_DIM + (bj * 4 + lj))) * 1024 + ch * 8;
    *(short8*)dst = val;
  }
}

// Kernel 3b: Z[cells][128] = O[cells][1024] @ Wf[128][1024]^T + b.
// 128-cell x 128-z tile (4 waves 2x2); K=1024 in 32 dbuf steps.
// R11: __launch_bounds__(256, 4) — LDS 32KB allows 5 blocks/CU; min-4
// guarantees all 576 blocks of a dispatch are co-resident (no tail round)
// and doubles the waves hiding the L3-latency O reads. VGPR 72 fits the
// 128/thread budget at 4 waves/SIMD.
__global__ __launch_bounds__(256, 4) void zgemm(
    const __hip_bfloat16* __restrict__ Og, const __hip_bfloat16* __restrict__ Wf,
    const float* __restrict__ b_final, float* __restrict__ out) {
  __shared__ __align__(16) char smem[32768];

  const int tid = threadIdx.x;
  const int wave = tid >> 6;
  const int lane = tid & 63;
  const int fr = lane & 15;
  const int fq = lane >> 4;
  const int fqs = fq ^ ((fr >> 1) & 3);
  const int wr = wave >> 1, wc = wave & 1;
  const size_t cell0 = (size_t)blockIdx.x * 128;

  const int srow = tid >> 2;
  const int sk = (((tid & 3) ^ ((tid >> 3) & 3)) * 8);
  const __hip_bfloat16* gO = Og + (cell0 + srow) * 1024 + sk;
  const __hip_bfloat16* gW = Wf + (size_t)srow * 1024 + sk;
  const int ldst = tid * 16;

  const f32x4 fzero = {0.f, 0.f, 0.f, 0.f};
  f32x4 acc[4][4];
#pragma unroll
  for (int i = 0; i < 4; ++i)
#pragma unroll
    for (int j = 0; j < 4; ++j) acc[i][j] = fzero;

  auto stage = [&](int kt, char* base) {
    const int k0 = kt * 32;
    async16(gO + k0, base + ldst);
    async16(gO + (size_t)64 * 1024 + k0, base + 4096 + ldst);
    async16(gW + k0, base + 8192 + ldst);
    async16(gW + (size_t)64 * 1024 + k0, base + 12288 + ldst);
  };
  auto compute = [&](const char* base) {
    const __hip_bfloat16* As = (const __hip_bfloat16*)base;          // O cells
    const __hip_bfloat16* Bs = (const __hip_bfloat16*)(base + 8192); // Wf rows
    short8 af[4], bfr[4];
#pragma unroll
    for (int mt = 0; mt < 4; ++mt)
      af[mt] = *(const short8*)(As + (wr * 64 + mt * 16 + fr) * 32 + fqs * 8);
#pragma unroll
    for (int nt = 0; nt < 4; ++nt)
      bfr[nt] = *(const short8*)(Bs + (wc * 64 + nt * 16 + fr) * 32 + fqs * 8);
#pragma unroll
    for (int mt = 0; mt < 4; ++mt)
#pragma unroll
      for (int nt = 0; nt < 4; ++nt)
        acc[mt][nt] = __builtin_amdgcn_mfma_f32_16x16x32_bf16(
            af[mt], bfr[nt], acc[mt][nt], 0, 0, 0);
  };

  char* buf0 = smem;
  char* buf1 = smem + 16384;
  stage(0, buf0);
  __syncthreads();
  for (int kt = 0; kt < 32; kt += 2) {
    stage(kt + 1, buf1);
    compute(buf0);
    __syncthreads();
    if (kt + 2 < 32) stage(kt + 2, buf0);
    compute(buf1);
    __syncthreads();
  }

  // Z write (+bias). D rows = cells, D cols = z.
#pragma unroll
  for (int nt = 0; nt < 4; ++nt) {
    const int zcol = wc * 64 + nt * 16 + fr;
    const float bz = b_final[zcol];
#pragma unroll
    for (int mt = 0; mt < 4; ++mt) {
      const size_t zrow = cell0 + wr * 64 + mt * 16 + fq * 4;
#pragma unroll
      for (int r = 0; r < 4; ++r)
        out[(zrow + r) * CZ_DIM + zcol] = acc[mt][nt][r] + bz;
    }
  }
}

// Legacy fused kernel (R3) — fallback when workspace can't hold any O slab.
__global__ __launch_bounds__(256, 2) void fused_opm(
    const __hip_bfloat16* __restrict__ Abt, const __hip_bfloat16* __restrict__ Bbt,
    const __hip_bfloat16* __restrict__ Wf, const float* __restrict__ b_final,
    float* __restrict__ out) {
  __shared__ __align__(16) char smem[32768];
  const int tid = threadIdx.x;
  const int wave = tid >> 6;
  const int lane = tid & 63;
  const int fr = lane & 15;
  const int fq = lane >> 4;
  const int fqs = fq ^ ((fr >> 1) & 3);
  const int wr = wave >> 1, wc = wave & 1;
  const int bi = blockIdx.y, bj = blockIdx.x;
  const size_t m0 = (size_t)bi * 128;
  const size_t n0 = (size_t)bj * 128;
  const int srow = tid >> 2;
  const int sk = (((tid & 3) ^ ((tid >> 3) & 3)) * 8);
  const __hip_bfloat16* gA = Abt + (m0 + srow) * N_DIM + sk;
  const __hip_bfloat16* gB = Bbt + (n0 + srow) * N_DIM + sk;
  const int ldst = tid * 16;

  const f32x4 fzero = {0.f, 0.f, 0.f, 0.f};
  f32x4 acc[4][4];
#pragma unroll
  for (int i = 0; i < 4; ++i)
#pragma unroll
    for (int j = 0; j < 4; ++j) acc[i][j] = fzero;

  auto stage = [&](int kt, char* base) {
    const int k0 = kt * 32;
    async16(gA + k0, base + ldst);
    async16(gA + (size_t)64 * N_DIM + k0, base + 4096 + ldst);
    async16(gB + k0, base + 8192 + ldst);
    async16(gB + (size_t)64 * N_DIM + k0, base + 12288 + ldst);
  };
  auto compute = [&](const char* base) {
    const __hip_bfloat16* As = (const __hip_bfloat16*)base;
    const __hip_bfloat16* Bs = (const __hip_bfloat16*)(base + 8192);
    short8 af[4], bfr[4];
#pragma unroll
    for (int mt = 0; mt < 4; ++mt)
      af[mt] = *(const short8*)(As + (wr * 64 + mt * 16 + fr) * 32 + fqs * 8);
#pragma unroll
    for (int nt = 0; nt < 4; ++nt)
      bfr[nt] = *(const short8*)(Bs + (wc * 64 + nt * 16 + fr) * 32 + fqs * 8);
#pragma unroll
    for (int mt = 0; mt < 4; ++mt)
#pragma unroll
      for (int nt = 0; nt < 4; ++nt)
        acc[mt][nt] = __builtin_amdgcn_mfma_f32_16x16x32_bf16(
            af[mt], bfr[nt], acc[mt][nt], 0, 0, 0);
  };

  char* buf0 = smem;
  char* buf1 = smem + 16384;
  stage(0, buf0);
  __syncthreads();
  for (int kt = 0; kt < 16; kt += 2) {
    stage(kt + 1, buf1);
    compute(buf0);
    __syncthreads();
    if (kt + 2 < 16) stage(kt + 2, buf0);
    compute(buf1);
    __syncthreads();
  }

  __hip_bfloat16* Oc = (__hip_bfloat16*)smem;  // [16][1024] slot-swizzled
#pragma unroll
  for (int mt = 0; mt < 4; ++mt) {
#pragma unroll
    for (int nt = 0; nt < 4; ++nt) {
      const int orow_b = wr * 64 + mt * 16 + fq * 4;
      const int ocol = wc * 64 + nt * 16 + fr;
#pragma unroll
      for (int r = 0; r < 4; ++r) {
        const int orow = orow_b + r;
        const int cell = ((orow >> 5) << 2) + (ocol >> 5);
        const int kk = ((orow & 31) << 5) + (ocol & 31);
        const int sw = ((((kk >> 3) ^ (cell & 7)) << 3) | (kk & 7));
        Oc[cell * 1024 + sw] = __float2bfloat16(acc[mt][nt][r]);
      }
    }
  }
  __syncthreads();

  f32x4 zacc0 = fzero, zacc1 = fzero;
  const int zt0 = wave * 2;
  const int xr = fr & 7;
  for (int kk = 0; kk < 32; ++kk) {
    const int slot = kk * 4 + fq;
    const short8 oa = *(const short8*)(Oc + fr * 1024 + ((slot ^ xr) << 3));
    const short8 wb0 =
        *(const short8*)(Wf + (size_t)((zt0 + 0) * 16 + fr) * 1024 + kk * 32 + fq * 8);
    const short8 wb1 =
        *(const short8*)(Wf + (size_t)((zt0 + 1) * 16 + fr) * 1024 + kk * 32 + fq * 8);
    zacc0 = __builtin_amdgcn_mfma_f32_16x16x32_bf16(oa, wb0, zacc0, 0, 0, 0);
    zacc1 = __builtin_amdgcn_mfma_f32_16x16x32_bf16(oa, wb1, zacc1, 0, 0, 0);
  }

  const int i0 = bi * 4, j0 = bj * 4;
#pragma unroll
  for (int t = 0; t < 2; ++t) {
    const int zcol = (zt0 + t) * 16 + fr;
    const float bz = b_final[zcol];
    const f32x4 za = t ? zacc1 : zacc0;
#pragma unroll
    for (int r = 0; r < 4; ++r) {
      const int cell = fq * 4 + r;
      const int li = cell >> 2, lj = cell & 3;
      out[((size_t)(i0 + li) * S_DIM + (j0 + lj)) * CZ_DIM + zcol] = za[r] + bz;
    }
  }
}

extern "C" void kernel_launch(void* const* d_in, const int* in_sizes, int n_in,
                              void* d_out, int out_size, void* d_ws, size_t ws_size,
                              hipStream_t stream) {
  const float* m_si = (const float*)d_in[0];
  const float* ln_g = (const float*)d_in[1];
  const float* ln_b = (const float*)d_in[2];
  const float* w_ab = (const float*)d_in[3];
  const float* w_final = (const float*)d_in[4];
  const float* b_final = (const float*)d_in[5];
  float* out = (float*)d_out;

  char* ws = (char*)d_ws;
  __hip_bfloat16* Abt = (__hip_bfloat16*)ws;                                // 12.58 MB
  __hip_bfloat16* Bbt = (__hip_bfloat16*)(ws + (size_t)MROWS * N_DIM * 2);  // 12.58 MB
  __hip_bfloat16* Wf = (__hip_bfloat16*)(ws + (size_t)MROWS * N_DIM * 4);   // 256 KB
  const size_t base = (size_t)MROWS * N_DIM * 4 + 262144;
  __hip_bfloat16* Og = (__hip_bfloat16*)(ws + base);

  prep_kernel<<<dim3(2, S_DIM), 256, 0, stream>>>(m_si, ln_g, ln_b, w_ab, Abt, Bbt);
  conv_wf<<<dim3((CZ_DIM * 1024) / 256), 256, 0, stream>>>(w_final, Wf);

  // Serial split (R9 structure, proven 367us): largest O slab that fits,
  // starting at nslab=2 (151 MB slab stays L3-resident between write+read).
  static const int cands[] = {2, 3, 4, 6, 8, 12, 16, 24, 32};
  int nslab = 0;
  for (int c : cands) {
    if (base + ((size_t)NCELL / c) * 1024 * 2 <= ws_size) { nslab = c; break; }
  }

  if (nslab) {
    const int biPer = 96 / nslab;                    // block-rows per slab
    const int cellsPer = NCELL / nslab;              // cells per slab
    for (int s = 0; s < nslab; ++s) {
      opm_main<<<dim3(96, biPer), 256, 0, stream>>>(Abt, Bbt, Og, s * biPer);
      zgemm<<<dim3(cellsPer / 128), 256, 0, stream>>>(
          Og, Wf, b_final, out + (size_t)s * cellsPer * CZ_DIM);
    }
  } else {
    fused_opm<<<dim3(96, 96), 256, 0, stream>>>(Abt, Bbt, Wf, b_final, out);
  }
}